// Round 5
// baseline (1763.278 us; speedup 1.0000x reference)
//
#include <hip/hip_runtime.h>

#define N_NODES 50000
#define N_EDGES 800000
#define D_FEAT 512
#define N_LAYERS 3
#define LN_EPS 1e-5f
#define M_PAD 50048  // 391 * 128
#define N_SBLK ((N_NODES + 255) / 256)  // 196 scan blocks

typedef __attribute__((ext_vector_type(8))) _Float16 half8;
typedef __attribute__((ext_vector_type(4))) _Float16 half4;
typedef __attribute__((ext_vector_type(4))) float f32x4;

__device__ __forceinline__ void gl_lds16(const unsigned short* g, unsigned short* l) {
  __builtin_amdgcn_global_load_lds((const __attribute__((address_space(1))) unsigned int*)g,
                                   (__attribute__((address_space(3))) unsigned int*)l, 16, 0, 0);
}

// ---------------- graph preprocessing ----------------

__global__ __launch_bounds__(256) void count_deg_kernel(const int* __restrict__ ei,
                                                        int* __restrict__ cnt) {
  int e = blockIdx.x * 256 + threadIdx.x;
  if (e < N_EDGES) atomicAdd(&cnt[ei[N_EDGES + e]], 1);
}

__global__ __launch_bounds__(256) void block_sum_kernel(const int* __restrict__ cnt,
                                                        int* __restrict__ bsum) {
  int i = blockIdx.x * 256 + threadIdx.x;
  int v = (i < N_NODES) ? cnt[i] : 0;
#pragma unroll
  for (int off = 32; off > 0; off >>= 1) v += __shfl_down(v, off);
  __shared__ int w[4];
  if ((threadIdx.x & 63) == 0) w[threadIdx.x >> 6] = v;
  __syncthreads();
  if (threadIdx.x == 0) bsum[blockIdx.x] = w[0] + w[1] + w[2] + w[3];
}

__global__ __launch_bounds__(256) void scan_bsum_kernel(const int* __restrict__ bsum,
                                                        int* __restrict__ boff,
                                                        int* __restrict__ rowoff) {
  __shared__ int sd[256];
  int t = threadIdx.x;
  int v = (t < N_SBLK) ? bsum[t] : 0;
  sd[t] = v;
  __syncthreads();
#pragma unroll
  for (int off = 1; off < 256; off <<= 1) {
    int x = (t >= off) ? sd[t - off] : 0;
    __syncthreads();
    sd[t] += x;
    __syncthreads();
  }
  if (t < N_SBLK) boff[t] = sd[t] - v;
  if (t == 255) rowoff[N_NODES] = sd[255];
}

__global__ __launch_bounds__(256) void scan_final_kernel(const int* __restrict__ cnt,
                                                         const int* __restrict__ boff,
                                                         int* __restrict__ rowoff,
                                                         float* __restrict__ inv_sqrt) {
  __shared__ int sd[256];
  int t = threadIdx.x;
  int i = blockIdx.x * 256 + t;
  int v = (i < N_NODES) ? cnt[i] : 0;
  sd[t] = v;
  __syncthreads();
#pragma unroll
  for (int off = 1; off < 256; off <<= 1) {
    int x = (t >= off) ? sd[t - off] : 0;
    __syncthreads();
    sd[t] += x;
    __syncthreads();
  }
  if (i < N_NODES) {
    rowoff[i] = boff[blockIdx.x] + sd[t] - v;
    inv_sqrt[i] = rsqrtf(1.0f + (float)v);
  }
}

__global__ __launch_bounds__(256) void fill_csr_kernel(const int* __restrict__ ei,
                                                       const int* __restrict__ rowoff,
                                                       int* __restrict__ cursor,
                                                       int* __restrict__ csr_src,
                                                       float* __restrict__ csr_w,
                                                       const float* __restrict__ inv_sqrt) {
  int e = blockIdx.x * 256 + threadIdx.x;
  if (e < N_EDGES) {
    int s = ei[e];
    int d = ei[N_EDGES + e];
    int p = atomicAdd(&cursor[d], 1);
    int slot = rowoff[d] + p;
    csr_src[slot] = s;
    csr_w[slot] = inv_sqrt[s] * inv_sqrt[d];
  }
}

// ---------------- fp32 -> split fp16 conversions ----------------

__global__ __launch_bounds__(256) void convert_x_kernel(const float* __restrict__ x,
                                                        _Float16* __restrict__ Ah,
                                                        _Float16* __restrict__ Al) {
  size_t i4 = ((size_t)blockIdx.x * 256 + threadIdx.x) * 4;
  int row = (int)(i4 >> 9);
  half4 h, l;
  if (row < N_NODES) {
    float4 v = *(const float4*)(x + i4);
    h[0] = (_Float16)v.x; l[0] = (_Float16)(v.x - (float)h[0]);
    h[1] = (_Float16)v.y; l[1] = (_Float16)(v.y - (float)h[1]);
    h[2] = (_Float16)v.z; l[2] = (_Float16)(v.z - (float)h[2]);
    h[3] = (_Float16)v.w; l[3] = (_Float16)(v.w - (float)h[3]);
  } else {
    h[0] = h[1] = h[2] = h[3] = (_Float16)0.f;
    l[0] = l[1] = l[2] = l[3] = (_Float16)0.f;
  }
  *(half4*)(Ah + i4) = h;
  *(half4*)(Al + i4) = l;
}

// W [k][n] fp32 -> Wt fp16 [n][k] (transposed, hi only)
__global__ __launch_bounds__(256) void wconv_kernel(const float* __restrict__ W,
                                                    _Float16* __restrict__ Bh) {
  __shared__ float t[64][65];
  int n0 = blockIdx.x * 64, k0 = blockIdx.y * 64;
  int tid = threadIdx.x;
  int c = tid & 63, r4 = tid >> 6;
#pragma unroll
  for (int r = 0; r < 64; r += 4)
    t[r4 + r][c] = W[(size_t)(k0 + r4 + r) * D_FEAT + n0 + c];
  __syncthreads();
#pragma unroll
  for (int r = 0; r < 64; r += 4) {
    float v = t[c][r4 + r];
    Bh[(size_t)(n0 + r4 + r) * D_FEAT + k0 + c] = (_Float16)v;
  }
}

// ---------------- split-fp16 MFMA GEMM: htc = fp16(A @ W + bias), chunked ----------------
// 128x128 tile, BK=32, 2 products: Ah*Bh + Al*Bh (B unsplit, fp16)

__global__ __launch_bounds__(256, 3) void mfma_gemm_kernel(
    const _Float16* __restrict__ Ah, const _Float16* __restrict__ Al,
    const _Float16* __restrict__ Bh, const float* __restrict__ bias,
    _Float16* __restrict__ htc) {
  __shared__ unsigned short sAh[128 * 32], sAl[128 * 32], sBh[128 * 32];

  int tid = threadIdx.x;
  int wave = tid >> 6, lane = tid & 63;
  int n0 = blockIdx.x * 128, m0 = blockIdx.y * 128;

  int r0 = (wave * 2 + 0) * 16 + (lane >> 2);
  int r1 = (wave * 2 + 1) * 16 + (lane >> 2);
  int s0 = (lane & 3) ^ ((r0 >> 1) & 3);
  int s1 = (lane & 3) ^ ((r1 >> 1) & 3);
  size_t gA0 = (size_t)(m0 + r0) * D_FEAT + s0 * 8;
  size_t gA1 = (size_t)(m0 + r1) * D_FEAT + s1 * 8;
  size_t gB0 = (size_t)(n0 + r0) * D_FEAT + s0 * 8;
  size_t gB1 = (size_t)(n0 + r1) * D_FEAT + s1 * 8;
  int l0 = (wave * 2 + 0) * 512;
  int l1 = (wave * 2 + 1) * 512;

  int q = lane >> 4, fr = lane & 15;
  int wm = (wave >> 1) * 64, wn = (wave & 1) * 64;
  int aoff[4], boff[4];
#pragma unroll
  for (int i = 0; i < 4; ++i) {
    int row = wm + i * 16 + fr;
    aoff[i] = row * 32 + (q ^ ((row >> 1) & 3)) * 8;
  }
#pragma unroll
  for (int j = 0; j < 4; ++j) {
    int row = wn + j * 16 + fr;
    boff[j] = row * 32 + (q ^ ((row >> 1) & 3)) * 8;
  }

  f32x4 acc[4][4];
#pragma unroll
  for (int i = 0; i < 4; ++i)
#pragma unroll
    for (int j = 0; j < 4; ++j) acc[i][j] = (f32x4)0.0f;

  for (int k0 = 0; k0 < D_FEAT; k0 += 32) {
    gl_lds16((const unsigned short*)(Ah + gA0 + k0), sAh + l0);
    gl_lds16((const unsigned short*)(Ah + gA1 + k0), sAh + l1);
    gl_lds16((const unsigned short*)(Al + gA0 + k0), sAl + l0);
    gl_lds16((const unsigned short*)(Al + gA1 + k0), sAl + l1);
    gl_lds16((const unsigned short*)(Bh + gB0 + k0), sBh + l0);
    gl_lds16((const unsigned short*)(Bh + gB1 + k0), sBh + l1);
    __syncthreads();

    half8 ah[4], al[4], bh[4];
#pragma unroll
    for (int i = 0; i < 4; ++i) ah[i] = *(const half8*)(sAh + aoff[i]);
#pragma unroll
    for (int i = 0; i < 4; ++i) al[i] = *(const half8*)(sAl + aoff[i]);
#pragma unroll
    for (int j = 0; j < 4; ++j) bh[j] = *(const half8*)(sBh + boff[j]);
#pragma unroll
    for (int i = 0; i < 4; ++i)
#pragma unroll
      for (int j = 0; j < 4; ++j)
        acc[i][j] = __builtin_amdgcn_mfma_f32_16x16x32_f16(ah[i], bh[j], acc[i][j], 0, 0, 0);
#pragma unroll
    for (int i = 0; i < 4; ++i)
#pragma unroll
      for (int j = 0; j < 4; ++j)
        acc[i][j] = __builtin_amdgcn_mfma_f32_16x16x32_f16(al[i], bh[j], acc[i][j], 0, 0, 0);
    __syncthreads();
  }

  float bj[4];
#pragma unroll
  for (int j = 0; j < 4; ++j) bj[j] = bias[n0 + wn + j * 16 + fr];
#pragma unroll
  for (int i = 0; i < 4; ++i) {
    int gm0 = m0 + wm + i * 16 + q * 4;
#pragma unroll
    for (int j = 0; j < 4; ++j) {
      int gn = n0 + wn + j * 16 + fr;
      int ch = gn >> 5, wi = gn & 31;
#pragma unroll
      for (int r = 0; r < 4; ++r) {
        int gm = gm0 + r;
        if (gm < N_NODES)
          htc[((size_t)ch * N_NODES + gm) * 32 + wi] = (_Float16)(acc[i][j][r] + bj[j]);
      }
    }
  }
}

// ---------------- XCD-partitioned aggregate (chunk = blockIdx.x & 7) ----------------
// wave per (node, 32-feat chunk): 8 edge-groups x 8 lanes x 4 feats.

__global__ __launch_bounds__(256) void agg_kernel(
    const _Float16* __restrict__ htc, const int* __restrict__ rowoff,
    const int* __restrict__ csr_src, const float* __restrict__ csr_w,
    const float* __restrict__ inv_sqrt, _Float16* __restrict__ aggc,
    float* __restrict__ stats, int chunk_base) {
  int wave = threadIdx.x >> 6, lane = threadIdx.x & 63;
  int chunk = chunk_base + (blockIdx.x & 7);
  int n = (blockIdx.x >> 3) * 4 + wave;
  int f4 = (lane & 7) * 4;
  int eg = lane >> 3;
  const _Float16* base = htc + (size_t)chunk * (N_NODES * 32);

  float a0 = 0.f, a1 = 0.f, a2 = 0.f, a3 = 0.f;
  if (eg == 0) {  // self-loop: ht[n] / deg, 1/deg == inv_sqrt[n]^2
    float isn = inv_sqrt[n];
    float ws = isn * isn;
    half4 v = *(const half4*)(base + (size_t)n * 32 + f4);
    a0 = ws * (float)v[0]; a1 = ws * (float)v[1];
    a2 = ws * (float)v[2]; a3 = ws * (float)v[3];
  }

  int beg = rowoff[n], end = rowoff[n + 1];
  for (int w0 = beg; w0 < end; w0 += 64) {
    int nw = end - w0;
    if (nw > 64) nw = 64;
    int sl = 0; float wl = 0.f;
    if (lane < nw) {
      sl = __builtin_nontemporal_load(csr_src + w0 + lane);
      wl = __builtin_nontemporal_load(csr_w + w0 + lane);
    }
    int iters = (nw + 7) >> 3;
    for (int i = 0; i < iters; ++i) {
      int ep = i * 8 + eg;
      int s = __shfl(sl, ep);
      float w = __shfl(wl, ep);
      if (ep < nw) {
        half4 v = *(const half4*)(base + (size_t)s * 32 + f4);
        a0 = fmaf(w, (float)v[0], a0);
        a1 = fmaf(w, (float)v[1], a1);
        a2 = fmaf(w, (float)v[2], a2);
        a3 = fmaf(w, (float)v[3], a3);
      }
    }
  }

  // reduce across the 8 edge-groups
#pragma unroll
  for (int off = 8; off < 64; off <<= 1) {
    a0 += __shfl_xor(a0, off);
    a1 += __shfl_xor(a1, off);
    a2 += __shfl_xor(a2, off);
    a3 += __shfl_xor(a3, off);
  }
  // partial LN stats over this chunk's 32 feats
  float s = a0 + a1 + a2 + a3;
  float s2 = a0 * a0 + a1 * a1 + a2 * a2 + a3 * a3;
#pragma unroll
  for (int off = 1; off < 8; off <<= 1) {
    s += __shfl_xor(s, off);
    s2 += __shfl_xor(s2, off);
  }
  if (lane == 0) {
    atomicAdd(&stats[n], s);
    atomicAdd(&stats[N_NODES + n], s2);
  }
  if (eg == 0) {
    half4 o;
    o[0] = (_Float16)a0; o[1] = (_Float16)a1;
    o[2] = (_Float16)a2; o[3] = (_Float16)a3;
    __builtin_nontemporal_store(o, (half4*)(aggc + ((size_t)chunk * N_NODES + n) * 32 + f4));
  }
}

// ---------------- LayerNorm + ReLU (+ fp16 split for next GEMM) ----------------

template <bool LAST>
__global__ __launch_bounds__(128) void ln_kernel(
    const _Float16* __restrict__ aggc, const float* __restrict__ stats,
    const float* __restrict__ gamma, const float* __restrict__ beta,
    float* __restrict__ out, _Float16* __restrict__ ph, _Float16* __restrict__ pl) {
  int n = blockIdx.x * 2 + (threadIdx.x >> 6);
  int lane = threadIdx.x & 63;
  int fb = lane * 8;
  half8 v = *(const half8*)(aggc + ((size_t)(lane >> 2) * N_NODES + n) * 32 + (lane & 3) * 8);

  const float inv_d = 1.0f / (float)D_FEAT;
  float mu = stats[n] * inv_d;
  float var = stats[N_NODES + n] * inv_d - mu * mu;
  float rstd = rsqrtf(var + LN_EPS);

  float4 g0 = *(const float4*)(gamma + fb);
  float4 g1 = *(const float4*)(gamma + fb + 4);
  float4 b0 = *(const float4*)(beta + fb);
  float4 b1 = *(const float4*)(beta + fb + 4);
  float gg[8] = {g0.x, g0.y, g0.z, g0.w, g1.x, g1.y, g1.z, g1.w};
  float bb[8] = {b0.x, b0.y, b0.z, b0.w, b1.x, b1.y, b1.z, b1.w};

  float o[8];
#pragma unroll
  for (int k = 0; k < 8; ++k)
    o[k] = fmaxf(gg[k] * ((float)v[k] - mu) * rstd + bb[k], 0.f);

  if (LAST) {
    *(float4*)(out + (size_t)n * D_FEAT + fb) = make_float4(o[0], o[1], o[2], o[3]);
    *(float4*)(out + (size_t)n * D_FEAT + fb + 4) = make_float4(o[4], o[5], o[6], o[7]);
  } else {
    half8 h, l;
#pragma unroll
    for (int k = 0; k < 8; ++k) {
      _Float16 hh = (_Float16)o[k];
      h[k] = hh;
      l[k] = (_Float16)(o[k] - (float)hh);
    }
    *(half8*)(ph + (size_t)n * D_FEAT + fb) = h;
    *(half8*)(pl + (size_t)n * D_FEAT + fb) = l;
  }
}

// ---------------- launch ----------------

extern "C" void kernel_launch(void* const* d_in, const int* in_sizes, int n_in,
                              void* d_out, int out_size, void* d_ws, size_t ws_size,
                              hipStream_t stream) {
  const float* x      = (const float*)d_in[0];
  const int*   ei     = (const int*)d_in[1];
  const float* Ws     = (const float*)d_in[2];
  const float* bs     = (const float*)d_in[3];
  const float* gammas = (const float*)d_in[4];
  const float* betas  = (const float*)d_in[5];
  float* out = (float*)d_out;

  _Float16* Ah   = (_Float16*)d_ws;                       // M_PAD*512
  _Float16* Al   = Ah + (size_t)M_PAD * D_FEAT;           // M_PAD*512
  _Float16* Bth  = Al + (size_t)M_PAD * D_FEAT;           // 512*512
  _Float16* htc  = Bth + (size_t)D_FEAT * D_FEAT;         // 16*N_NODES*32 chunked
  _Float16* aggc = htc + (size_t)16 * N_NODES * 32;       // 16*N_NODES*32 chunked
  float* stats3  = (float*)(aggc + (size_t)16 * N_NODES * 32);  // 3*2*N_NODES
  float* csr_w   = stats3 + 3 * 2 * N_NODES;              // N_EDGES
  float* inv_sqrt = csr_w + N_EDGES;                      // N_NODES
  int* deg_cnt = (int*)(inv_sqrt + N_NODES);
  int* rowoff  = deg_cnt + N_NODES;
  int* cursor  = rowoff + (N_NODES + 1);
  int* csr_src = cursor + N_NODES;
  int* bsum    = csr_src + N_EDGES;
  int* boff    = bsum + N_SBLK;

  hipMemsetAsync(deg_cnt, 0, N_NODES * sizeof(int), stream);
  hipMemsetAsync(cursor, 0, N_NODES * sizeof(int), stream);
  hipMemsetAsync(stats3, 0, 3 * 2 * N_NODES * sizeof(float), stream);

  count_deg_kernel<<<(N_EDGES + 255) / 256, 256, 0, stream>>>(ei, deg_cnt);
  block_sum_kernel<<<N_SBLK, 256, 0, stream>>>(deg_cnt, bsum);
  scan_bsum_kernel<<<1, 256, 0, stream>>>(bsum, boff, rowoff);
  scan_final_kernel<<<N_SBLK, 256, 0, stream>>>(deg_cnt, boff, rowoff, inv_sqrt);
  fill_csr_kernel<<<(N_EDGES + 255) / 256, 256, 0, stream>>>(ei, rowoff, cursor, csr_src,
                                                             csr_w, inv_sqrt);

  convert_x_kernel<<<(M_PAD * D_FEAT / 4) / 256, 256, 0, stream>>>(x, Ah, Al);

  dim3 ggrid(D_FEAT / 128, M_PAD / 128);
  for (int l = 0; l < N_LAYERS; ++l) {
    float* stats_l = stats3 + (size_t)l * 2 * N_NODES;
    wconv_kernel<<<dim3(8, 8), 256, 0, stream>>>(Ws + (size_t)l * D_FEAT * D_FEAT, Bth);
    mfma_gemm_kernel<<<ggrid, 256, 0, stream>>>(Ah, Al, Bth, bs + (size_t)l * D_FEAT, htc);
    // two phases of 8 chunks: XCD c (heuristic bid%8) stays on one 3.2MB slice
    agg_kernel<<<(N_NODES / 4) * 8, 256, 0, stream>>>(htc, rowoff, csr_src, csr_w,
                                                      inv_sqrt, aggc, stats_l, 0);
    agg_kernel<<<(N_NODES / 4) * 8, 256, 0, stream>>>(htc, rowoff, csr_src, csr_w,
                                                      inv_sqrt, aggc, stats_l, 8);
    if (l < N_LAYERS - 1) {
      ln_kernel<false><<<N_NODES / 2, 128, 0, stream>>>(
          aggc, stats_l, gammas + (size_t)l * D_FEAT, betas + (size_t)l * D_FEAT,
          nullptr, Ah, Al);
    } else {
      ln_kernel<true><<<N_NODES / 2, 128, 0, stream>>>(
          aggc, stats_l, gammas + (size_t)l * D_FEAT, betas + (size_t)l * D_FEAT,
          out, nullptr, nullptr);
    }
  }
}

// Round 6
// 934.634 us; speedup vs baseline: 1.8866x; 1.8866x over previous
//
#include <hip/hip_runtime.h>

#define N_NODES 50000
#define N_EDGES 800000
#define D_FEAT 512
#define N_LAYERS 3
#define LN_EPS 1e-5f
#define M_PAD 50048  // 391 * 128
#define N_SBLK ((N_NODES + 255) / 256)  // 196 scan blocks

typedef __attribute__((ext_vector_type(8))) _Float16 half8;
typedef __attribute__((ext_vector_type(4))) _Float16 half4;
typedef __attribute__((ext_vector_type(4))) float f32x4;

__device__ __forceinline__ void gl_lds16(const unsigned short* g, unsigned short* l) {
  __builtin_amdgcn_global_load_lds((const __attribute__((address_space(1))) unsigned int*)g,
                                   (__attribute__((address_space(3))) unsigned int*)l, 16, 0, 0);
}

// ---------------- graph preprocessing ----------------

__global__ __launch_bounds__(256) void count_deg_kernel(const int* __restrict__ ei,
                                                        int* __restrict__ cnt) {
  int e = blockIdx.x * 256 + threadIdx.x;
  if (e < N_EDGES) atomicAdd(&cnt[ei[N_EDGES + e]], 1);
}

__global__ __launch_bounds__(256) void block_sum_kernel(const int* __restrict__ cnt,
                                                        int* __restrict__ bsum) {
  int i = blockIdx.x * 256 + threadIdx.x;
  int v = (i < N_NODES) ? cnt[i] : 0;
#pragma unroll
  for (int off = 32; off > 0; off >>= 1) v += __shfl_down(v, off);
  __shared__ int w[4];
  if ((threadIdx.x & 63) == 0) w[threadIdx.x >> 6] = v;
  __syncthreads();
  if (threadIdx.x == 0) bsum[blockIdx.x] = w[0] + w[1] + w[2] + w[3];
}

__global__ __launch_bounds__(256) void scan_bsum_kernel(const int* __restrict__ bsum,
                                                        int* __restrict__ boff,
                                                        int* __restrict__ rowoff) {
  __shared__ int sd[256];
  int t = threadIdx.x;
  int v = (t < N_SBLK) ? bsum[t] : 0;
  sd[t] = v;
  __syncthreads();
#pragma unroll
  for (int off = 1; off < 256; off <<= 1) {
    int x = (t >= off) ? sd[t - off] : 0;
    __syncthreads();
    sd[t] += x;
    __syncthreads();
  }
  if (t < N_SBLK) boff[t] = sd[t] - v;
  if (t == 255) rowoff[N_NODES] = sd[255];
}

__global__ __launch_bounds__(256) void scan_final_kernel(const int* __restrict__ cnt,
                                                         const int* __restrict__ boff,
                                                         int* __restrict__ rowoff,
                                                         float* __restrict__ inv_sqrt) {
  __shared__ int sd[256];
  int t = threadIdx.x;
  int i = blockIdx.x * 256 + t;
  int v = (i < N_NODES) ? cnt[i] : 0;
  sd[t] = v;
  __syncthreads();
#pragma unroll
  for (int off = 1; off < 256; off <<= 1) {
    int x = (t >= off) ? sd[t - off] : 0;
    __syncthreads();
    sd[t] += x;
    __syncthreads();
  }
  if (i < N_NODES) {
    rowoff[i] = boff[blockIdx.x] + sd[t] - v;
    inv_sqrt[i] = rsqrtf(1.0f + (float)v);
  }
}

// packed CSR entry: .x = src index, .y = float bits of enorm weight
__global__ __launch_bounds__(256) void fill_csr_kernel(const int* __restrict__ ei,
                                                       const int* __restrict__ rowoff,
                                                       int* __restrict__ cursor,
                                                       int2* __restrict__ csr_pk,
                                                       const float* __restrict__ inv_sqrt) {
  int e = blockIdx.x * 256 + threadIdx.x;
  if (e < N_EDGES) {
    int s = ei[e];
    int d = ei[N_EDGES + e];
    int p = atomicAdd(&cursor[d], 1);
    int2 pk;
    pk.x = s;
    pk.y = __float_as_int(inv_sqrt[s] * inv_sqrt[d]);
    csr_pk[rowoff[d] + p] = pk;
  }
}

// ---------------- fp32 -> split fp16 conversions ----------------

__global__ __launch_bounds__(256) void convert_x_kernel(const float* __restrict__ x,
                                                        _Float16* __restrict__ Ah,
                                                        _Float16* __restrict__ Al) {
  size_t i4 = ((size_t)blockIdx.x * 256 + threadIdx.x) * 4;
  int row = (int)(i4 >> 9);
  half4 h, l;
  if (row < N_NODES) {
    float4 v = *(const float4*)(x + i4);
    h[0] = (_Float16)v.x; l[0] = (_Float16)(v.x - (float)h[0]);
    h[1] = (_Float16)v.y; l[1] = (_Float16)(v.y - (float)h[1]);
    h[2] = (_Float16)v.z; l[2] = (_Float16)(v.z - (float)h[2]);
    h[3] = (_Float16)v.w; l[3] = (_Float16)(v.w - (float)h[3]);
  } else {
    h[0] = h[1] = h[2] = h[3] = (_Float16)0.f;
    l[0] = l[1] = l[2] = l[3] = (_Float16)0.f;
  }
  *(half4*)(Ah + i4) = h;
  *(half4*)(Al + i4) = l;
}

// W [k][n] fp32 -> Wt fp16 [n][k] (transposed)
__global__ __launch_bounds__(256) void wconv_kernel(const float* __restrict__ W,
                                                    _Float16* __restrict__ Bh) {
  __shared__ float t[64][65];
  int n0 = blockIdx.x * 64, k0 = blockIdx.y * 64;
  int tid = threadIdx.x;
  int c = tid & 63, r4 = tid >> 6;
#pragma unroll
  for (int r = 0; r < 64; r += 4)
    t[r4 + r][c] = W[(size_t)(k0 + r4 + r) * D_FEAT + n0 + c];
  __syncthreads();
#pragma unroll
  for (int r = 0; r < 64; r += 4) {
    float v = t[c][r4 + r];
    Bh[(size_t)(n0 + r4 + r) * D_FEAT + k0 + c] = (_Float16)v;
  }
}

// ---------------- split-fp16 MFMA GEMM: ht[M,512] = fp16(A @ W + bias) ----------------
// 128x128 tile, BK=32, 2 products: Ah*Bh + Al*Bh

__global__ __launch_bounds__(256, 3) void mfma_gemm_kernel(
    const _Float16* __restrict__ Ah, const _Float16* __restrict__ Al,
    const _Float16* __restrict__ Bh, const float* __restrict__ bias,
    _Float16* __restrict__ ht) {
  __shared__ unsigned short sAh[128 * 32], sAl[128 * 32], sBh[128 * 32];

  int tid = threadIdx.x;
  int wave = tid >> 6, lane = tid & 63;
  int n0 = blockIdx.x * 128, m0 = blockIdx.y * 128;  // N tiles adjacent -> A reuse

  int r0 = (wave * 2 + 0) * 16 + (lane >> 2);
  int r1 = (wave * 2 + 1) * 16 + (lane >> 2);
  int s0 = (lane & 3) ^ ((r0 >> 1) & 3);
  int s1 = (lane & 3) ^ ((r1 >> 1) & 3);
  size_t gA0 = (size_t)(m0 + r0) * D_FEAT + s0 * 8;
  size_t gA1 = (size_t)(m0 + r1) * D_FEAT + s1 * 8;
  size_t gB0 = (size_t)(n0 + r0) * D_FEAT + s0 * 8;
  size_t gB1 = (size_t)(n0 + r1) * D_FEAT + s1 * 8;
  int l0 = (wave * 2 + 0) * 512;
  int l1 = (wave * 2 + 1) * 512;

  int q = lane >> 4, fr = lane & 15;
  int wm = (wave >> 1) * 64, wn = (wave & 1) * 64;
  int aoff[4], boff[4];
#pragma unroll
  for (int i = 0; i < 4; ++i) {
    int row = wm + i * 16 + fr;
    aoff[i] = row * 32 + (q ^ ((row >> 1) & 3)) * 8;
  }
#pragma unroll
  for (int j = 0; j < 4; ++j) {
    int row = wn + j * 16 + fr;
    boff[j] = row * 32 + (q ^ ((row >> 1) & 3)) * 8;
  }

  f32x4 acc[4][4];
#pragma unroll
  for (int i = 0; i < 4; ++i)
#pragma unroll
    for (int j = 0; j < 4; ++j) acc[i][j] = (f32x4)0.0f;

  for (int k0 = 0; k0 < D_FEAT; k0 += 32) {
    gl_lds16((const unsigned short*)(Ah + gA0 + k0), sAh + l0);
    gl_lds16((const unsigned short*)(Ah + gA1 + k0), sAh + l1);
    gl_lds16((const unsigned short*)(Al + gA0 + k0), sAl + l0);
    gl_lds16((const unsigned short*)(Al + gA1 + k0), sAl + l1);
    gl_lds16((const unsigned short*)(Bh + gB0 + k0), sBh + l0);
    gl_lds16((const unsigned short*)(Bh + gB1 + k0), sBh + l1);
    __syncthreads();

    half8 ah[4], al[4], bh[4];
#pragma unroll
    for (int i = 0; i < 4; ++i) ah[i] = *(const half8*)(sAh + aoff[i]);
#pragma unroll
    for (int i = 0; i < 4; ++i) al[i] = *(const half8*)(sAl + aoff[i]);
#pragma unroll
    for (int j = 0; j < 4; ++j) bh[j] = *(const half8*)(sBh + boff[j]);
#pragma unroll
    for (int i = 0; i < 4; ++i)
#pragma unroll
      for (int j = 0; j < 4; ++j)
        acc[i][j] = __builtin_amdgcn_mfma_f32_16x16x32_f16(ah[i], bh[j], acc[i][j], 0, 0, 0);
#pragma unroll
    for (int i = 0; i < 4; ++i)
#pragma unroll
      for (int j = 0; j < 4; ++j)
        acc[i][j] = __builtin_amdgcn_mfma_f32_16x16x32_f16(al[i], bh[j], acc[i][j], 0, 0, 0);
    __syncthreads();
  }

  float bj[4];
#pragma unroll
  for (int j = 0; j < 4; ++j) bj[j] = bias[n0 + wn + j * 16 + fr];
#pragma unroll
  for (int i = 0; i < 4; ++i) {
    int gm0 = m0 + wm + i * 16 + q * 4;
#pragma unroll
    for (int j = 0; j < 4; ++j) {
      int gn = n0 + wn + j * 16 + fr;
#pragma unroll
      for (int r = 0; r < 4; ++r) {
        int gm = gm0 + r;
        if (gm < N_NODES)
          ht[(size_t)gm * D_FEAT + gn] = (_Float16)(acc[i][j][r] + bj[j]);
      }
    }
  }
}

// ---------------- fused aggregate + self-loop + LayerNorm + ReLU ----------------
// one wave per node; lane owns 8 consecutive feats (16B); packed (src,w) CSR; unroll x4.

template <bool LAST>
__global__ __launch_bounds__(256) void agg_ln_relu_kernel(
    const _Float16* __restrict__ ht, const int* __restrict__ rowoff,
    const int2* __restrict__ csr_pk, const float* __restrict__ inv_sqrt,
    const float* __restrict__ gamma, const float* __restrict__ beta,
    float* __restrict__ hout, _Float16* __restrict__ ph, _Float16* __restrict__ pl) {
  int n = blockIdx.x * 4 + (threadIdx.x >> 6);
  int lane = threadIdx.x & 63;
  int c8 = lane * 8;

  float acc[8];
#pragma unroll
  for (int k = 0; k < 8; ++k) acc[k] = 0.f;

  int beg = rowoff[n];
  int end = rowoff[n + 1];

  int e = beg;
  for (; e + 4 <= end; e += 4) {
    int2 p0 = csr_pk[e], p1 = csr_pk[e + 1], p2 = csr_pk[e + 2], p3 = csr_pk[e + 3];
    half8 v0 = *(const half8*)(ht + (size_t)p0.x * D_FEAT + c8);
    half8 v1 = *(const half8*)(ht + (size_t)p1.x * D_FEAT + c8);
    half8 v2 = *(const half8*)(ht + (size_t)p2.x * D_FEAT + c8);
    half8 v3 = *(const half8*)(ht + (size_t)p3.x * D_FEAT + c8);
    float w0 = __int_as_float(p0.y), w1 = __int_as_float(p1.y);
    float w2 = __int_as_float(p2.y), w3 = __int_as_float(p3.y);
#pragma unroll
    for (int k = 0; k < 8; ++k) acc[k] = fmaf(w0, (float)v0[k], acc[k]);
#pragma unroll
    for (int k = 0; k < 8; ++k) acc[k] = fmaf(w1, (float)v1[k], acc[k]);
#pragma unroll
    for (int k = 0; k < 8; ++k) acc[k] = fmaf(w2, (float)v2[k], acc[k]);
#pragma unroll
    for (int k = 0; k < 8; ++k) acc[k] = fmaf(w3, (float)v3[k], acc[k]);
  }
  for (; e < end; ++e) {
    int2 p = csr_pk[e];
    half8 v = *(const half8*)(ht + (size_t)p.x * D_FEAT + c8);
    float w = __int_as_float(p.y);
#pragma unroll
    for (int k = 0; k < 8; ++k) acc[k] = fmaf(w, (float)v[k], acc[k]);
  }
  {
    float isn = inv_sqrt[n];
    float w = isn * isn;  // self-loop 1/deg
    half8 v = *(const half8*)(ht + (size_t)n * D_FEAT + c8);
#pragma unroll
    for (int k = 0; k < 8; ++k) acc[k] = fmaf(w, (float)v[k], acc[k]);
  }

  float s = 0.f, s2 = 0.f;
#pragma unroll
  for (int k = 0; k < 8; ++k) { s += acc[k]; s2 += acc[k] * acc[k]; }
#pragma unroll
  for (int off = 32; off > 0; off >>= 1) {
    s += __shfl_xor(s, off);
    s2 += __shfl_xor(s2, off);
  }

  const float inv_d = 1.0f / (float)D_FEAT;
  float mu = s * inv_d;
  float var = s2 * inv_d - mu * mu;
  float rstd = rsqrtf(var + LN_EPS);

  float4 g0 = *(const float4*)(gamma + c8);
  float4 g1 = *(const float4*)(gamma + c8 + 4);
  float4 b0 = *(const float4*)(beta + c8);
  float4 b1 = *(const float4*)(beta + c8 + 4);
  float gg[8] = {g0.x, g0.y, g0.z, g0.w, g1.x, g1.y, g1.z, g1.w};
  float bb[8] = {b0.x, b0.y, b0.z, b0.w, b1.x, b1.y, b1.z, b1.w};

  float o[8];
#pragma unroll
  for (int k = 0; k < 8; ++k)
    o[k] = fmaxf(gg[k] * (acc[k] - mu) * rstd + bb[k], 0.f);

  if (LAST) {
    *(float4*)(hout + (size_t)n * D_FEAT + c8) = make_float4(o[0], o[1], o[2], o[3]);
    *(float4*)(hout + (size_t)n * D_FEAT + c8 + 4) = make_float4(o[4], o[5], o[6], o[7]);
  } else {
    half8 h, l;
#pragma unroll
    for (int k = 0; k < 8; ++k) {
      _Float16 hh = (_Float16)o[k];
      h[k] = hh;
      l[k] = (_Float16)(o[k] - (float)hh);
    }
    size_t off = (size_t)n * D_FEAT + c8;
    *(half8*)(ph + off) = h;
    *(half8*)(pl + off) = l;
  }
}

// ---------------- launch ----------------

extern "C" void kernel_launch(void* const* d_in, const int* in_sizes, int n_in,
                              void* d_out, int out_size, void* d_ws, size_t ws_size,
                              hipStream_t stream) {
  const float* x      = (const float*)d_in[0];
  const int*   ei     = (const int*)d_in[1];
  const float* Ws     = (const float*)d_in[2];
  const float* bs     = (const float*)d_in[3];
  const float* gammas = (const float*)d_in[4];
  const float* betas  = (const float*)d_in[5];
  float* out = (float*)d_out;

  _Float16* Ah  = (_Float16*)d_ws;                      // M_PAD*512
  _Float16* Al  = Ah + (size_t)M_PAD * D_FEAT;          // M_PAD*512
  _Float16* Bth = Al + (size_t)M_PAD * D_FEAT;          // 512*512
  _Float16* htb = Bth + (size_t)D_FEAT * D_FEAT;        // N_NODES*512 fp16
  int2* csr_pk  = (int2*)(htb + (size_t)N_NODES * D_FEAT);  // N_EDGES int2
  float* inv_sqrt = (float*)(csr_pk + N_EDGES);         // N_NODES
  int* deg_cnt = (int*)(inv_sqrt + N_NODES);
  int* rowoff  = deg_cnt + N_NODES;
  int* cursor  = rowoff + (N_NODES + 1);
  int* bsum    = cursor + N_NODES;
  int* boff    = bsum + N_SBLK;

  hipMemsetAsync(deg_cnt, 0, N_NODES * sizeof(int), stream);
  hipMemsetAsync(cursor, 0, N_NODES * sizeof(int), stream);

  count_deg_kernel<<<(N_EDGES + 255) / 256, 256, 0, stream>>>(ei, deg_cnt);
  block_sum_kernel<<<N_SBLK, 256, 0, stream>>>(deg_cnt, bsum);
  scan_bsum_kernel<<<1, 256, 0, stream>>>(bsum, boff, rowoff);
  scan_final_kernel<<<N_SBLK, 256, 0, stream>>>(deg_cnt, boff, rowoff, inv_sqrt);
  fill_csr_kernel<<<(N_EDGES + 255) / 256, 256, 0, stream>>>(ei, rowoff, cursor,
                                                             csr_pk, inv_sqrt);

  convert_x_kernel<<<(M_PAD * D_FEAT / 4) / 256, 256, 0, stream>>>(x, Ah, Al);

  dim3 ggrid(D_FEAT / 128, M_PAD / 128);
  for (int l = 0; l < N_LAYERS; ++l) {
    wconv_kernel<<<dim3(8, 8), 256, 0, stream>>>(Ws + (size_t)l * D_FEAT * D_FEAT, Bth);
    mfma_gemm_kernel<<<ggrid, 256, 0, stream>>>(Ah, Al, Bth, bs + (size_t)l * D_FEAT, htb);
    if (l < N_LAYERS - 1) {
      agg_ln_relu_kernel<false><<<N_NODES / 4, 256, 0, stream>>>(
          htb, rowoff, csr_pk, inv_sqrt, gammas + (size_t)l * D_FEAT,
          betas + (size_t)l * D_FEAT, nullptr, Ah, Al);
    } else {
      agg_ln_relu_kernel<true><<<N_NODES / 4, 256, 0, stream>>>(
          htb, rowoff, csr_pk, inv_sqrt, gammas + (size_t)l * D_FEAT,
          betas + (size_t)l * D_FEAT, out, nullptr, nullptr);
    }
  }
}